// Round 8
// baseline (2645.566 us; speedup 1.0000x reference)
//
#include <hip/hip_runtime.h>

#define BB 64
#define TT 1000
#define II 16
#define HH 512
#define OO 8
#define NOISE_STD 0.05f
#define ALPHA 0.2f

#define NGROUPS 32   // batch groups (independent sync domains)
#define BPG 2        // batches per group
#define NSLABS 8     // row slabs (WGs) per group
#define JS 64        // rows per slab
#define NTHREADS 512 // 8 waves; wave w owns k-slice [w*64, w*64+64)
#define NBLOCKS (NGROUPS * NSLABS)   // 256 = one WG per CU

// d_ws layout (1 MB):
//   rtagB[2][BB][HH] u64 @ 0      — agent-scope (MALL) slots: the PROVEN path
//   rtagA[2][BB][HH] u64 @ 512KB  — fast mirror: plain stores -> producer-XCD L2
// Each slot = (tag<<32 | r_bits). Equality-tag protocol: a slot awaiting tag t
// can only contain {stale != t, t}; 0xAA poison never matches. Consumers poll
// the fast mirror but escalate to the agent slot every 4th try, so progress
// NEVER depends on sc0/L2 semantics (round-7 hang designed out). Addresses are
// separate so dirty fast-mirror writebacks can never regress the agent slot.

__global__ void __launch_bounds__(NTHREADS, 1) rnn_kernel(
    const float* __restrict__ x, const float* __restrict__ noise,
    const float* __restrict__ wi, const float* __restrict__ si,
    const float* __restrict__ wrec, const float* __restrict__ wo,
    const float* __restrict__ so, const float* __restrict__ h0,
    float* __restrict__ out, unsigned long long* rtagB, unsigned long long* rtagA)
{
    __shared__ __align__(16) float rlds[2][BPG][HH];          // for out-waves  8 KB
    __shared__ __align__(16) float zpart[2][NSLABS][BPG][JS]; // parity-dbuf    8 KB
    __shared__ __align__(16) float xpbuf[2][BPG][JS];         //                1 KB

    const int tid  = threadIdx.x;
    const int lane = tid & 63;
    const int wid  = tid >> 6;

    // XCD-packing: all 8 slabs of a group share (blockIdx.x & 7) -> same XCD
    // under round-robin dispatch. Heuristic only; correctness path is agent-scope.
    const int xcd  = blockIdx.x & 7;
    const int bidx = blockIdx.x >> 3;         // 0..31
    const int grp  = xcd * 4 + (bidx >> 3);   // 0..31
    const int slab = bidx & 7;                // 0..7
    const int gb   = grp * BPG;
    const int j0   = slab * JS;

    // ---- one-time staging ----
    float w_reg[64];   // wrec row (j0+lane), k-slice [wid*64, +64)
    {
        const float4* wrow = (const float4*)(wrec + (size_t)(j0 + lane) * HH + wid * 64);
        #pragma unroll
        for (int c = 0; c < 16; ++c) {
            float4 v = wrow[c];
            w_reg[4*c+0] = v.x; w_reg[4*c+1] = v.y;
            w_reg[4*c+2] = v.z; w_reg[4*c+3] = v.w;
        }
    }

    float hreg = 0.f;
    if (wid < BPG) hreg = h0[j0 + lane];      // h for (batch gb+wid, row j0+lane)

    float wiF_r[16];                           // waves 6,7: x-projection weights
    if (wid >= 6) {
        #pragma unroll
        for (int i = 0; i < 16; ++i) wiF_r[i] = si[i] * wi[i * HH + j0 + lane];
    }
    float wo_r[8][8];                          // waves 4,5: output weights
    if (wid == 4 || wid == 5) {
        float so_[8];
        #pragma unroll
        for (int o = 0; o < 8; ++o) so_[o] = so[o];
        #pragma unroll
        for (int m = 0; m < 8; ++m) {
            const float4* wrow = (const float4*)(wo + (size_t)(lane + 64 * m) * OO);
            float4 wa = wrow[0], wb2 = wrow[1];
            wo_r[m][0] = wa.x  * so_[0]; wo_r[m][1] = wa.y  * so_[1];
            wo_r[m][2] = wa.z  * so_[2]; wo_r[m][3] = wa.w  * so_[3];
            wo_r[m][4] = wb2.x * so_[4]; wo_r[m][5] = wb2.y * so_[5];
            wo_r[m][6] = wb2.z * so_[6]; wo_r[m][7] = wb2.w * so_[7];
        }
    }

    // r_0 = tanh(h0): own slice in regs + staged for out waves
    unsigned int rb0, rb1;
    {
        float rv = tanhf(h0[wid * 64 + lane]);
        rb0 = __float_as_uint(rv);
        rb1 = rb0;
        rlds[0][0][wid * 64 + lane] = rv;
        rlds[0][1][wid * 64 + lane] = rv;
    }
    if (wid >= 6) {
        const int b = wid - 6;
        const float4* xb = (const float4*)(x + ((size_t)(gb + b) * TT + 0) * II);
        float4 x0 = xb[0], x1 = xb[1], x2 = xb[2], x3 = xb[3];
        xpbuf[0][b][lane] =
              x0.x*wiF_r[0]  + x0.y*wiF_r[1]  + x0.z*wiF_r[2]  + x0.w*wiF_r[3]
            + x1.x*wiF_r[4]  + x1.y*wiF_r[5]  + x1.z*wiF_r[6]  + x1.w*wiF_r[7]
            + x2.x*wiF_r[8]  + x2.y*wiF_r[9]  + x2.z*wiF_r[10] + x2.w*wiF_r[11]
            + x3.x*wiF_r[12] + x3.y*wiF_r[13] + x3.z*wiF_r[14] + x3.w*wiF_r[15];
    }
    __syncthreads();

    for (int t = 0; t < TT; ++t) {
        const int par = t & 1;
        const int nxt = (t + 1) & 1;

        float nz = 0.f;
        if (wid < BPG)
            nz = noise[((size_t)(gb + wid) * TT + t) * HH + j0 + lane];

        // per-wave rendezvous: poll OWN slice (tag == t), keep r in VGPRs.
        // Fast sc0 polls on the L2 mirror; every 4th try reads the agent slot
        // (guaranteed visible) -> cannot hang.
        if (t > 0) {
            const size_t base = (size_t)par * (BB * HH) + (size_t)gb * HH
                              + wid * 64 + lane;
            const unsigned long long* sB = rtagB + base;
            const unsigned long long aA0 = (unsigned long long)(uintptr_t)(rtagA + base);
            const unsigned long long aA1 = (unsigned long long)(uintptr_t)(rtagA + base + HH);
            unsigned long long v0, v1;
            const unsigned int tg = (unsigned int)t;
            int it = 0;
            do {
                if ((it & 3) == 3) {
                    v0 = __hip_atomic_load(sB,      __ATOMIC_RELAXED, __HIP_MEMORY_SCOPE_AGENT);
                    v1 = __hip_atomic_load(sB + HH, __ATOMIC_RELAXED, __HIP_MEMORY_SCOPE_AGENT);
                } else {
                    asm volatile("global_load_dwordx2 %0, %2, off sc0\n\t"
                                 "global_load_dwordx2 %1, %3, off sc0\n\t"
                                 "s_waitcnt vmcnt(0)"
                                 : "=&v"(v0), "=&v"(v1)
                                 : "v"(aA0), "v"(aA1) : "memory");
                }
                ++it;
            } while ((unsigned int)(v0 >> 32) != tg || (unsigned int)(v1 >> 32) != tg);
            rb0 = (unsigned int)v0;
            rb1 = (unsigned int)v1;
            rlds[par][0][wid * 64 + lane] = __uint_as_float(rb0);
            rlds[par][1][wid * 64 + lane] = __uint_as_float(rb1);
        }

        // matvec on own slice: w in regs, r broadcast via v_readlane
        float a0 = 0.f, a1 = 0.f;
        #pragma unroll
        for (int c = 0; c < 64; ++c) {
            float r0 = __uint_as_float(__builtin_amdgcn_readlane(rb0, c));
            float r1 = __uint_as_float(__builtin_amdgcn_readlane(rb1, c));
            a0 += w_reg[c] * r0;
            a1 += w_reg[c] * r1;
        }
        zpart[par][wid][0][lane] = a0;
        zpart[par][wid][1][lane] = a1;
        __syncthreads();   // S1 (only barrier): zpart[par] + rlds[par] ready

        if (wid < BPG) {
            // reduce 8 k-slices + h-update + double publish (b=wid, j=lane)
            float z = 0.f;
            #pragma unroll
            for (int k8 = 0; k8 < 8; ++k8) z += zpart[par][k8][wid][lane];
            float xp = xpbuf[par][wid][lane];
            float hn = hreg + NOISE_STD * nz + ALPHA * (z + xp - hreg);
            hreg = hn;
            float rnew = tanhf(hn);
            unsigned long long pv =
                ((unsigned long long)(unsigned int)(t + 1) << 32)
              | (unsigned long long)__float_as_uint(rnew);
            const size_t dbase = (size_t)nxt * (BB * HH)
                               + (size_t)(gb + wid) * HH + j0 + lane;
            // fast mirror: plain store -> this XCD's L2 (same-XCD sc0 readers)
            const unsigned long long adA = (unsigned long long)(uintptr_t)(rtagA + dbase);
            asm volatile("global_store_dwordx2 %0, %1, off"
                         :: "v"(adA), "v"(pv) : "memory");
            // sure path: agent-scope -> MALL (round-6 proven)
            __hip_atomic_store(rtagB + dbase, pv, __ATOMIC_RELAXED,
                               __HIP_MEMORY_SCOPE_AGENT);
        } else if (wid == 4 || wid == 5) {
            // out[t-1] = r_t @ wo_full — off the critical path
            const int b = wid - 4;
            if (t > 0) {
                float acc0=0.f,acc1=0.f,acc2=0.f,acc3=0.f,
                      acc4=0.f,acc5=0.f,acc6=0.f,acc7=0.f;
                #pragma unroll
                for (int m = 0; m < 8; ++m) {
                    float rv = rlds[par][b][lane + 64 * m];
                    acc0 += rv * wo_r[m][0]; acc1 += rv * wo_r[m][1];
                    acc2 += rv * wo_r[m][2]; acc3 += rv * wo_r[m][3];
                    acc4 += rv * wo_r[m][4]; acc5 += rv * wo_r[m][5];
                    acc6 += rv * wo_r[m][6]; acc7 += rv * wo_r[m][7];
                }
                float res = 0.f;
                #define RED_(A, O) { float v_ = A; \
                    v_ += __shfl_xor(v_, 1);  v_ += __shfl_xor(v_, 2); \
                    v_ += __shfl_xor(v_, 4);  v_ += __shfl_xor(v_, 8); \
                    v_ += __shfl_xor(v_, 16); v_ += __shfl_xor(v_, 32); \
                    if (lane == O) res = v_; }
                RED_(acc0, 0) RED_(acc1, 1) RED_(acc2, 2) RED_(acc3, 3)
                RED_(acc4, 4) RED_(acc5, 5) RED_(acc6, 6) RED_(acc7, 7)
                #undef RED_
                if (lane < 8)
                    out[((size_t)(gb + b) * TT + (t - 1)) * OO + lane] = res;
            }
        } else if (wid >= 6) {
            // x-projection for step t+1 (off critical path)
            const int b = wid - 6;
            if (t + 1 < TT) {
                const float4* xb =
                    (const float4*)(x + ((size_t)(gb + b) * TT + (t + 1)) * II);
                float4 x0 = xb[0], x1 = xb[1], x2 = xb[2], x3 = xb[3];
                xpbuf[nxt][b][lane] =
                      x0.x*wiF_r[0]  + x0.y*wiF_r[1]  + x0.z*wiF_r[2]  + x0.w*wiF_r[3]
                    + x1.x*wiF_r[4]  + x1.y*wiF_r[5]  + x1.z*wiF_r[6]  + x1.w*wiF_r[7]
                    + x2.x*wiF_r[8]  + x2.y*wiF_r[9]  + x2.z*wiF_r[10] + x2.w*wiF_r[11]
                    + x3.x*wiF_r[12] + x3.y*wiF_r[13] + x3.z*wiF_r[14] + x3.w*wiF_r[15];
            }
        }
        // waves 2,3 have nothing post-S1 -> they loop and poll t+1 early
    }

    // epilogue: poll r_TT (parity 0, tag TT), stage, emit out[TT-1]
    {
        const size_t base = (size_t)gb * HH + wid * 64 + lane;   // parity 0
        const unsigned long long* sB = rtagB + base;
        const unsigned long long aA0 = (unsigned long long)(uintptr_t)(rtagA + base);
        const unsigned long long aA1 = (unsigned long long)(uintptr_t)(rtagA + base + HH);
        unsigned long long v0, v1;
        const unsigned int tg = (unsigned int)TT;
        int it = 0;
        do {
            if ((it & 3) == 3) {
                v0 = __hip_atomic_load(sB,      __ATOMIC_RELAXED, __HIP_MEMORY_SCOPE_AGENT);
                v1 = __hip_atomic_load(sB + HH, __ATOMIC_RELAXED, __HIP_MEMORY_SCOPE_AGENT);
            } else {
                asm volatile("global_load_dwordx2 %0, %2, off sc0\n\t"
                             "global_load_dwordx2 %1, %3, off sc0\n\t"
                             "s_waitcnt vmcnt(0)"
                             : "=&v"(v0), "=&v"(v1)
                             : "v"(aA0), "v"(aA1) : "memory");
            }
            ++it;
        } while ((unsigned int)(v0 >> 32) != tg || (unsigned int)(v1 >> 32) != tg);
        rlds[0][0][wid * 64 + lane] = __uint_as_float((unsigned int)v0);
        rlds[0][1][wid * 64 + lane] = __uint_as_float((unsigned int)v1);
    }
    __syncthreads();
    if (wid == 4 || wid == 5) {
        const int b = wid - 4;
        float acc0=0.f,acc1=0.f,acc2=0.f,acc3=0.f,acc4=0.f,acc5=0.f,acc6=0.f,acc7=0.f;
        #pragma unroll
        for (int m = 0; m < 8; ++m) {
            float rv = rlds[0][b][lane + 64 * m];
            acc0 += rv * wo_r[m][0]; acc1 += rv * wo_r[m][1];
            acc2 += rv * wo_r[m][2]; acc3 += rv * wo_r[m][3];
            acc4 += rv * wo_r[m][4]; acc5 += rv * wo_r[m][5];
            acc6 += rv * wo_r[m][6]; acc7 += rv * wo_r[m][7];
        }
        float res = 0.f;
        #define RED_(A, O) { float v_ = A; \
            v_ += __shfl_xor(v_, 1);  v_ += __shfl_xor(v_, 2); \
            v_ += __shfl_xor(v_, 4);  v_ += __shfl_xor(v_, 8); \
            v_ += __shfl_xor(v_, 16); v_ += __shfl_xor(v_, 32); \
            if (lane == O) res = v_; }
        RED_(acc0, 0) RED_(acc1, 1) RED_(acc2, 2) RED_(acc3, 3)
        RED_(acc4, 4) RED_(acc5, 5) RED_(acc6, 6) RED_(acc7, 7)
        #undef RED_
        if (lane < 8)
            out[((size_t)(gb + b) * TT + (TT - 1)) * OO + lane] = res;
    }
}

extern "C" void kernel_launch(void* const* d_in, const int* in_sizes, int n_in,
                              void* d_out, int out_size, void* d_ws, size_t ws_size,
                              hipStream_t stream) {
    const float* x     = (const float*)d_in[0];
    const float* noise = (const float*)d_in[1];
    const float* wi    = (const float*)d_in[2];
    const float* si    = (const float*)d_in[3];
    const float* wrec  = (const float*)d_in[4];
    const float* wo    = (const float*)d_in[5];
    const float* so    = (const float*)d_in[6];
    const float* h0    = (const float*)d_in[7];
    float* out = (float*)d_out;
    unsigned long long* rtagB = (unsigned long long*)d_ws;        // 512 KB (agent)
    unsigned long long* rtagA = rtagB + 2 * BB * HH;              // 512 KB (L2 mirror)

    (void)in_sizes; (void)n_in; (void)out_size; (void)ws_size;

    void* args[] = {(void*)&x, (void*)&noise, (void*)&wi, (void*)&si,
                    (void*)&wrec, (void*)&wo, (void*)&so, (void*)&h0,
                    (void*)&out, (void*)&rtagB, (void*)&rtagA};
    hipLaunchCooperativeKernel((void*)rnn_kernel, dim3(NBLOCKS), dim3(NTHREADS),
                               args, 0, stream);
}